// Round 1
// baseline (6598.261 us; speedup 1.0000x reference)
//
#include <hip/hip_runtime.h>
#include <math.h>

#define BB 16
#define LL 128
#define HH 1024
#define EE 512
#define VV 32000
#define G3 3072

__device__ __forceinline__ float sigmoidf_(float x){ return 1.0f/(1.0f+expf(-x)); }

// Build row index: enc row r = (l,b) -> token = input[b*L + l]
__global__ void k_rowidx(const int* __restrict__ inp, int* __restrict__ idx){
  int r = blockIdx.x*256 + threadIdx.x;
  if (r < 2048){ int l = r >> 4, b = r & 15; idx[r] = inp[b*LL + l]; }
}

// Generic tiled GEMM: C[r][c] = act(bias[c] + sum_k A[row(r)][k]*Bm[k][c])
// block: 32 rows x 512 cols; 256 threads, 2 cols (float2) x 32 rows each.
template<int ACT, int KK>
__global__ __launch_bounds__(256) void k_gemm(const float* __restrict__ A, const int* __restrict__ rowidx,
                       const float* __restrict__ Bm, const float* __restrict__ bias,
                       float* __restrict__ C, int N){
  constexpr int KS = (KK==512)?9:10;
  __shared__ float As[32*KK];
  const int tid = threadIdx.x;
  const int r0 = blockIdx.x*32;
  const int c  = blockIdx.y*512 + (tid<<1);
  for (int i = tid; i < 32*KK; i += 256){
    int rr = i >> KS;
    int row = r0 + rr;
    int arow = rowidx ? rowidx[row] : row;
    int kk = i - (rr<<KS);
    As[i] = A[(size_t)arow*KK + kk];
  }
  __syncthreads();
  float2 acc[32];
  #pragma unroll
  for (int r=0;r<32;r++){ acc[r].x=0.f; acc[r].y=0.f; }
  for (int k=0;k<KK;k++){
    const float2 w = *(const float2*)(Bm + (size_t)k*N + c);
    #pragma unroll
    for (int r=0;r<32;r++){
      float a = As[(r<<KS)+k];
      acc[r].x = fmaf(a,w.x,acc[r].x);
      acc[r].y = fmaf(a,w.y,acc[r].y);
    }
  }
  const float2 bv = *(const float2*)(bias + c);
  #pragma unroll
  for (int r=0;r<32;r++){
    float x = acc[r].x + bv.x, y = acc[r].y + bv.y;
    if (ACT==1){ x = tanhf(x); y = tanhf(y); }
    *(float2*)(C + (size_t)(r0+r)*N + c) = make_float2(x,y);
  }
}

// gx0[j] = bih0[j] + sum_k emb[SOS=1][k] * Wih0[k][j]
__global__ void k_gx0(const float* __restrict__ emb, const float* __restrict__ Wih0,
                      const float* __restrict__ bih0, float* __restrict__ gx0){
  int j = blockIdx.x*256 + threadIdx.x;
  float acc = bih0[j];
  const float* e = emb + EE;  // row of SOS index 1
  for (int k=0;k<EE;k++) acc = fmaf(e[k], Wih0[(size_t)k*G3 + j], acc);
  gx0[j] = acc;
}

// One GRU recurrence step: gh = Hin @ Whh (+bhh), gates with gx, Hout = GRU update.
// grid 256 blocks (4 hidden cols each), 256 threads = (kc 0..63) x (jl 0..3).
__global__ __launch_bounds__(256,1) void k_chain(const float* __restrict__ Hin, float* __restrict__ Hout,
                        const float* __restrict__ W, const float* __restrict__ gxbase, int gxbstride,
                        const float* __restrict__ bhh){
  __shared__ float hs[16][HH+1];   // padded: conflict-free
  __shared__ float part[192*65];
  __shared__ float red[192];
  const int tid = threadIdx.x;
  const int kc = tid >> 2;
  const int jl = tid & 3;
  const int jb = blockIdx.x << 2;
  for (int i = tid; i < 16*HH; i += 256){
    int b = i >> 10, k = i & 1023;
    hs[b][k] = Hin[i];
  }
  __syncthreads();
  float acc[3][16];
  #pragma unroll
  for (int g=0; g<3; g++)
    #pragma unroll
    for (int b=0;b<16;b++) acc[g][b]=0.f;
  const float* wbase = W + jb + jl;
  for (int it=0; it<16; it++){
    int k = (it<<6) + kc;                 // strided k: 16 lanes -> 16 banks
    const float* wr = wbase + (size_t)k*G3;
    float w0 = wr[0], w1 = wr[1024], w2 = wr[2048];
    #pragma unroll
    for (int b=0;b<16;b++){
      float h = hs[b][k];
      acc[0][b] = fmaf(w0,h,acc[0][b]);
      acc[1][b] = fmaf(w1,h,acc[1][b]);
      acc[2][b] = fmaf(w2,h,acc[2][b]);
    }
  }
  #pragma unroll
  for (int g=0;g<3;g++)
    #pragma unroll
    for (int b=0;b<16;b++)
      part[((g*16+b)*4 + jl)*65 + kc] = acc[g][b];
  __syncthreads();
  if (tid < 192){
    float s = 0.f;
    const float* p = part + tid*65;
    #pragma unroll
    for (int kk=0;kk<64;kk++) s += p[kk];
    red[tid] = s;
  }
  __syncthreads();
  if (tid < 64){
    int b = tid >> 2, o = tid & 3;
    int j = jb + o;
    float ghr = red[(0*16+b)*4+o] + bhh[j];
    float ghz = red[(1*16+b)*4+o] + bhh[1024+j];
    float ghn = red[(2*16+b)*4+o] + bhh[2048+j];
    const float* gx = gxbase + (size_t)b*gxbstride;
    float r = sigmoidf_(gx[j] + ghr);
    float z = sigmoidf_(gx[1024+j] + ghz);
    float n = tanhf(gx[2048+j] + r*ghn);
    Hout[b*HH + j] = (1.f-z)*n + z*hs[b][j];
  }
}

// Batched attention: per block (s_chunk of 8, b): scores -> softmax -> ctx
__global__ __launch_bounds__(256) void k_attn(const float* __restrict__ enc, const float* __restrict__ H1,
                       float* __restrict__ ctx){
  __shared__ float h1s[8][HH];
  __shared__ float sc[8][LL];
  __shared__ float part[2][8][LL];
  const int tid = threadIdx.x;
  const int s0 = blockIdx.x*8, b = blockIdx.y;
  for (int i = tid; i < 8*HH; i += 256){
    int si = i >> 10, k = i & 1023;
    h1s[si][k] = H1[(size_t)(s0+si)*BB*HH + (size_t)b*HH + k];
  }
  __syncthreads();
  {
    const int l = tid & 127, half = tid >> 7;
    const float4* er = (const float4*)(enc + ((size_t)l*BB + b)*HH + half*512);
    float a[8];
    #pragma unroll
    for (int s=0;s<8;s++) a[s]=0.f;
    for (int q=0;q<128;q++){
      float4 e = er[q];
      #pragma unroll
      for (int s=0;s<8;s++){
        const float4 h = *(const float4*)(&h1s[s][half*512 + q*4]);
        a[s] += h.x*e.x + h.y*e.y + h.z*e.z + h.w*e.w;
      }
    }
    #pragma unroll
    for (int s=0;s<8;s++) part[half][s][l] = a[s];
  }
  __syncthreads();
  for (int p = tid; p < 1024; p += 256){
    int s = p >> 7, l = p & 127;
    sc[s][l] = (part[0][s][l] + part[1][s][l]) * 0.03125f;   // 1/sqrt(1024)
  }
  __syncthreads();
  {
    int s = tid >> 5, lid = tid & 31;
    float v0 = sc[s][lid], v1 = sc[s][lid+32], v2 = sc[s][lid+64], v3 = sc[s][lid+96];
    float m = fmaxf(fmaxf(v0,v1),fmaxf(v2,v3));
    for (int off=16; off>=1; off>>=1) m = fmaxf(m, __shfl_xor(m, off, 32));
    float e0=__expf(v0-m), e1=__expf(v1-m), e2=__expf(v2-m), e3=__expf(v3-m);
    float ssum = e0+e1+e2+e3;
    for (int off=16; off>=1; off>>=1) ssum += __shfl_xor(ssum, off, 32);
    float inv = 1.0f/ssum;
    sc[s][lid]=e0*inv; sc[s][lid+32]=e1*inv; sc[s][lid+64]=e2*inv; sc[s][lid+96]=e3*inv;
  }
  __syncthreads();
  {
    float acc[4][8];
    #pragma unroll
    for (int q=0;q<4;q++)
      #pragma unroll
      for (int s=0;s<8;s++) acc[q][s]=0.f;
    for (int l=0;l<128;l++){
      const float* er = enc + ((size_t)l*BB + b)*HH + tid;
      float a[8];
      #pragma unroll
      for (int s=0;s<8;s++) a[s] = sc[s][l];
      #pragma unroll
      for (int q=0;q<4;q++){
        float e = er[q*256];
        #pragma unroll
        for (int s=0;s<8;s++) acc[q][s] = fmaf(a[s], e, acc[q][s]);
      }
    }
    #pragma unroll
    for (int s=0;s<8;s++)
      #pragma unroll
      for (int q=0;q<4;q++)
        ctx[(size_t)(s0+s)*BB*HH + (size_t)b*HH + tid + q*256] = acc[q][s];
  }
}

// Gathered logits + sigmoid + BCE: one block per (b,t)
__global__ __launch_bounds__(256) void k_logit(const float* __restrict__ H1, const float* __restrict__ ctx,
                        const float* __restrict__ Wout, const float* __restrict__ bout,
                        const int* __restrict__ inp, const int* __restrict__ ts,
                        float* __restrict__ outp, float* __restrict__ bce){
  __shared__ float rbuf[256];
  const int i = blockIdx.x;
  const int b = i >> 7, t = i & 127;
  const int v = inp[b*LL + t];
  const int tid = threadIdx.x;
  const float* h1r = H1 + ((size_t)t*BB + b)*HH;
  const float* cxr = ctx + ((size_t)t*BB + b)*HH;
  float acc = 0.f;
  #pragma unroll
  for (int q=0;q<4;q++){
    int k = tid + q*256;
    acc = fmaf(h1r[k], Wout[(size_t)k*VV + v], acc);
  }
  #pragma unroll
  for (int q=0;q<4;q++){
    int k = tid + q*256;
    acc = fmaf(cxr[k], Wout[(size_t)(k+1024)*VV + v], acc);
  }
  rbuf[tid] = acc;
  __syncthreads();
  for (int s=128; s>0; s>>=1){
    if (tid < s) rbuf[tid] += rbuf[tid+s];
    __syncthreads();
  }
  if (tid==0){
    float logit = rbuf[0] + bout[v];
    float p = 1.0f/(1.0f + expf(-logit));
    outp[b*LL + t] = p;
    float pc = fminf(fmaxf(p, 1e-12f), 1.0f - 1e-7f);
    float tg = (float)ts[0];
    bce[i] = -(tg*logf(pc) + (1.0f-tg)*log1pf(-pc));
  }
}

__global__ void k_loss(const float* __restrict__ bce, float* __restrict__ out0){
  __shared__ float rbuf[256];
  int tid = threadIdx.x;
  float s = 0.f;
  for (int i = tid; i < 2048; i += 256) s += bce[i];
  rbuf[tid] = s; __syncthreads();
  for (int st=128; st>0; st>>=1){
    if (tid<st) rbuf[tid]+=rbuf[tid+st];
    __syncthreads();
  }
  if (tid==0) out0[0] = rbuf[0] * (1.0f/(2048.0f*16.0f));
}

extern "C" void kernel_launch(void* const* d_in, const int* in_sizes, int n_in,
                              void* d_out, int out_size, void* d_ws, size_t ws_size,
                              hipStream_t stream){
  (void)in_sizes; (void)n_in; (void)out_size; (void)ws_size;
  const int*   inp   = (const int*)d_in[0];
  const int*   ts    = (const int*)d_in[2];
  const float* emb   = (const float*)d_in[3];
  const float* encW  = (const float*)d_in[4];
  const float* encb  = (const float*)d_in[5];
  const float* Wih0  = (const float*)d_in[6];
  const float* Whh0  = (const float*)d_in[7];
  const float* bih0  = (const float*)d_in[8];
  const float* bhh0  = (const float*)d_in[9];
  const float* Wih1  = (const float*)d_in[10];
  const float* Whh1  = (const float*)d_in[11];
  const float* bih1  = (const float*)d_in[12];
  const float* bhh1  = (const float*)d_in[13];
  const float* Wout  = (const float*)d_in[14];
  const float* bout  = (const float*)d_in[15];
  float* out = (float*)d_out;

  float* ws      = (float*)d_ws;
  float* enc_out = ws;                         // [128][16][1024]
  float* H0      = enc_out + 2097152;          // [128][16][1024] (h0 after step s)
  float* H1      = H0 + 2097152;               // [128][16][1024]
  float* GX1     = H1 + 2097152;               // [128][16][3072]
  float* CTX     = GX1 + 6291456;              // [128][16][1024]
  float* gx0     = CTX + 2097152;              // [3072]
  float* bceb    = gx0 + 3072;                 // [2048]
  int*   rowidx  = (int*)(bceb + 2048);        // [2048]

  k_rowidx<<<8,256,0,stream>>>(inp, rowidx);
  // Encoder: enc_out[l][b][:] = tanh(emb[token] @ encW + encb)
  k_gemm<1,512><<<dim3(64,2),256,0,stream>>>(emb, rowidx, encW, encb, enc_out, HH);
  k_gx0<<<12,256,0,stream>>>(emb, Wih0, bih0, gx0);

  const float* enclast = enc_out + (size_t)127*BB*HH;  // h_init

  // Chain 0: h0 recurrence (constant SOS input -> gx0 broadcast)
  for (int s=0;s<128;s++){
    const float* hin = (s==0) ? enclast : (H0 + (size_t)(s-1)*BB*HH);
    k_chain<<<256,256,0,stream>>>(hin, H0 + (size_t)s*BB*HH, Whh0, gx0, 0, bhh0);
  }
  // Batched GX1 = H0_all @ Wih1 + bih1
  k_gemm<0,1024><<<dim3(64,6),256,0,stream>>>(H0, nullptr, Wih1, bih1, GX1, G3);
  // Chain 1: h1 recurrence
  for (int s=0;s<128;s++){
    const float* hin = (s==0) ? enclast : (H1 + (size_t)(s-1)*BB*HH);
    k_chain<<<256,256,0,stream>>>(hin, H1 + (size_t)s*BB*HH, Whh1,
                                  GX1 + (size_t)s*BB*G3, G3, bhh1);
  }
  // Batched attention (scores -> softmax -> ctx) for all steps
  k_attn<<<dim3(16,16),256,0,stream>>>(enc_out, H1, CTX);
  // Gathered logits + sigmoid + bce; then loss reduction
  k_logit<<<2048,256,0,stream>>>(H1, CTX, Wout, bout, inp, ts, out+1, bceb);
  k_loss<<<1,256,0,stream>>>(bceb, out);
}